// Round 12
// baseline (975.111 us; speedup 1.0000x reference)
//
#include <hip/hip_runtime.h>
#include <hip/hip_cooperative_groups.h>

// Block_58394375356873: HomoAttention transformer block, MI355X gfx950.
// I/O dtype: float32 (per reference). Internal GEMM compute: bf16 MFMA.
// M = B*N = 64*196 = 12544.
//
// R12: cooperative phase-chaining. Ledger shows ~80-95us of inter-dispatch
// overhead across 7 dispatches (kernel interiors sum to ~310us vs 403 total).
// coopA = [LN1+weights] sync [qk]; coopB = [LN2] sync [fc1] sync [fc2];
// 256 blocks x 512 thr (1 block/CU at 128KB LDS = exactly co-resident).
// GEMM interior = byte-identical R11 gemm8p body (device function).
// Fallback to the verified R11 sequence if cooperative launch errors.

#define BATCH 64
#define SEQ   196
#define CH    768
#define NHEAD 12
#define HDIM  64
#define TOPK  16
#define HID   3072
#define MROWS 12544
#define MHALF 6272
#define SCALE_F 0.125f  // 64^-0.5
#define NEGBIG -3e38f

namespace cg = cooperative_groups;

typedef __bf16 bf16x8 __attribute__((ext_vector_type(8)));
typedef float  f32x4  __attribute__((ext_vector_type(4)));

__device__ __forceinline__ unsigned short f2b(float f) {
    union { float f; unsigned int i; } c; c.f = f;
    unsigned int u = c.i;
    return (unsigned short)((u + 0x7fffu + ((u >> 16) & 1u)) >> 16); // RNE
}
__device__ __forceinline__ float b2f(unsigned short u) {
    union { unsigned int i; float f; } c; c.i = ((unsigned int)u) << 16; return c.f;
}

// single-VALU median-of-3 (v_med3_f32; VOP3, all-VGPR operands)
__device__ __forceinline__ float med3(float a, float b, float c) {
    float r;
    asm("v_med3_f32 %0, %1, %2, %3" : "=v"(r) : "v"(a), "v"(b), "v"(c));
    return r;
}

// tanh-form GELU, |err vs exact erf-GELU| < 4e-4, ~10 VALU ops.
__device__ __forceinline__ float gelu_f(float v) {
    float u = v * (0.7978845608f + 0.0356774081f * v * v);
    float e = __expf(2.0f * u);
    float th = 1.0f - 2.0f / (e + 1.0f);
    return 0.5f * v * (1.0f + th);
}

// async global->LDS, 16B per lane. LDS base must be wave-uniform; HW adds lane*16.
__device__ __forceinline__ void async16(const unsigned short* g, unsigned short* l) {
    __builtin_amdgcn_global_load_lds(
        (const __attribute__((address_space(1))) unsigned int*)(g),
        (__attribute__((address_space(3))) unsigned int*)(l), 16, 0, 0);
}

// ================= LN phase at 512 thr: 49 rows/block, 2 rows/iter =================
template<bool INF32>
__device__ __forceinline__ void ln_phase(const void* __restrict__ xin,
                                         const float* __restrict__ gw,
                                         const float* __restrict__ bw,
                                         unsigned short* __restrict__ out,
                                         float* red)
{
    const int tid  = threadIdx.x;
    const int half = tid >> 8;          // waves 0-3 -> 0, waves 4-7 -> 1
    const int t    = tid & 255;
    const int base = (int)blockIdx.x * 49;
#pragma unroll 1
    for (int i = 0; i < 49; i += 2) {
        const int ri = i + half;
        const bool valid = ri < 49;
        const int row = base + ri;
        float v0 = 0.f, v1 = 0.f, v2 = 0.f;
        if (valid) {
            if constexpr (INF32) {
                const float* xr = (const float*)xin + (size_t)row * CH;
                v0 = xr[t]; v1 = xr[t + 256]; v2 = xr[t + 512];
            } else {
                const unsigned short* xr = (const unsigned short*)xin + (size_t)row * CH;
                v0 = b2f(xr[t]); v1 = b2f(xr[t + 256]); v2 = b2f(xr[t + 512]);
            }
        }
        float s  = v0 + v1 + v2;
        float sq = v0*v0 + v1*v1 + v2*v2;
#pragma unroll
        for (int off = 32; off > 0; off >>= 1) {
            s  += __shfl_down(s, off, 64);
            sq += __shfl_down(sq, off, 64);
        }
        if ((tid & 63) == 0) { red[(tid >> 6) * 2] = s; red[(tid >> 6) * 2 + 1] = sq; }
        __syncthreads();
        s  = red[half * 8 + 0] + red[half * 8 + 2] + red[half * 8 + 4] + red[half * 8 + 6];
        sq = red[half * 8 + 1] + red[half * 8 + 3] + red[half * 8 + 5] + red[half * 8 + 7];
        __syncthreads();
        if (valid) {
            float mu  = s * (1.0f / CH);
            float var = sq * (1.0f / CH) - mu * mu;
            float rs  = rsqrtf(var + 1e-5f);
            unsigned short* orow = out + (size_t)row * CH;
            orow[t]       = f2b((v0 - mu) * rs * gw[t]       + bw[t]);
            orow[t + 256] = f2b((v1 - mu) * rs * gw[t + 256] + bw[t + 256]);
            orow[t + 512] = f2b((v2 - mu) * rs * gw[t + 512] + bw[t + 512]);
        }
    }
}

// ================= weight-convert phase, grid-stride at 256x512 =================
__device__ __forceinline__ void conv_phase(const float* s0, unsigned short* d0, int n0,
                                           const float* s1, unsigned short* d1, int n1,
                                           const float* s2, unsigned short* d2, int n2,
                                           const float* s3, unsigned short* d3, int n3)
{
    const int total4 = (n0 + n1 + n2 + n3) >> 2;
    for (int b4 = (int)blockIdx.x * 512 + (int)threadIdx.x; b4 < total4; b4 += 256 * 512) {
        int idx = b4 * 4;
        const float* s; unsigned short* d; int n;
        if (idx < n0) { s = s0; d = d0; n = n0; }
        else {
            idx -= n0;
            if (idx < n1) { s = s1; d = d1; n = n1; }
            else {
                idx -= n1;
                if (idx < n2) { s = s2; d = d2; n = n2; }
                else { idx -= n2; s = s3; d = d3; n = n3; }
            }
        }
        if (idx < n) {
            float4 v = *(const float4*)(s + idx);
            ushort4 o;
            o.x = f2b(v.x); o.y = f2b(v.y); o.z = f2b(v.z); o.w = f2b(v.w);
            *(ushort4*)(d + idx) = o;
        }
    }
}

// ========== Persistent 4-phase 256x256 NT GEMM body (R4/R11-exact, bf16) ==========
// LDS passed in: AsP/BsP each 2*16384 shorts (double-buffered 256x64 tiles).
template<int KC, bool BIAS, int RES, bool GELU, bool OUTF>
__device__ void gemm8p_body(const unsigned short* __restrict__ A,
                            const unsigned short* __restrict__ Bw,
                            const float* __restrict__ bias,
                            const void* __restrict__ resid,
                            void* __restrict__ Cout,
                            int M, int N,
                            unsigned short* AsP, unsigned short* BsP)
{
    constexpr int T = KC / 64;
    static_assert((T & 1) == 0, "T must be even for persistent parity");
    const int tid  = threadIdx.x;
    const int w    = tid >> 6;
    const int lane = tid & 63;
    const int q    = lane >> 4;
    const int l16  = lane & 15;

    const int gridN = N >> 8, gridM = M >> 8;
    const int nt = gridN * gridM;
    const int P = gridDim.x;

    auto tileOf = [&](int lid2, int& tm, int& tn) {
        const int SG = 8 * gridN;
        const int sg = lid2 / SG, rr2 = lid2 % SG;
        const int remM = gridM - sg * 8;
        int mloc, nloc;
        if (remM >= 8) { mloc = sg * 8 + (rr2 & 7); nloc = rr2 >> 3; }
        else           { mloc = sg * 8 + rr2 % remM; nloc = rr2 / remM; }
        tm = mloc * 256; tn = nloc * 256;
    };

    const int wm = (w >> 2) * 128;
    const int wn = (w & 3) * 64;

    const int r0 = tid >> 3;
    const int g0 = (tid & 7) ^ (r0 & 7);
    const int rB = r0 + (r0 & 32);

    const int arow = wm + l16;
    const int brow = wn + l16;
    const int xsw  = l16 & 7;

    for (int t = (int)blockIdx.x; t < nt; t += P) {
        int tileM, tileN;
        tileOf(t, tileM, tileN);
        const bool hasNext = (t + P) < nt;
        int tileM2 = tileM, tileN2 = tileN;
        if (hasNext) tileOf(t + P, tileM2, tileN2);

        const unsigned short* pA0  = A  + (size_t)(tileM  + r0) * KC + g0 * 8;
        const unsigned short* pB0  = Bw + (size_t)(tileN  + rB) * KC + g0 * 8;
        const unsigned short* pA0n = A  + (size_t)(tileM2 + r0) * KC + g0 * 8;
        const unsigned short* pB0n = Bw + (size_t)(tileN2 + rB) * KC + g0 * 8;

        auto stageA = [&](int v, int j) {
            const unsigned short* base = (v == T) ? pA0n : pA0;
            const int vv = (v == T) ? 0 : v;
            const unsigned short* s = base + (size_t)(j * 64) * KC + vv * 64;
            unsigned short* d = AsP + (vv & 1) * 16384 + j * 4096 + w * 512;
            async16(s, d);
            async16(s + (size_t)128 * KC, d + 8192);
        };
        auto stageB = [&](int v, int j) {
            const unsigned short* base = (v == T) ? pB0n : pB0;
            const int vv = (v == T) ? 0 : v;
            const unsigned short* s = base + (size_t)(j * 32) * KC + vv * 64;
            unsigned short* d = BsP + (vv & 1) * 16384 + j * 2048 + (w * 8 + ((w & 4) << 3)) * 64;
            async16(s, d);
            async16(s + (size_t)128 * KC, d + 8192);
        };

        f32x4 acc[8][4];
#pragma unroll
        for (int i = 0; i < 8; ++i)
#pragma unroll
            for (int jn = 0; jn < 4; ++jn) acc[i][jn] = (f32x4){0.f, 0.f, 0.f, 0.f};

        if (t == (int)blockIdx.x) {
            stageA(0, 0); stageB(0, 0); stageB(0, 1); stageA(0, 1);
            asm volatile("s_waitcnt vmcnt(4)" ::: "memory");
            __builtin_amdgcn_s_barrier();
            asm volatile("" ::: "memory");
        }

#pragma unroll 2
        for (int u = 0; u < T; ++u) {
            const unsigned short* Ab = AsP + (u & 1) * 16384;
            const unsigned short* Bb = BsP + (u & 1) * 16384;
            const bool more = (u + 1 < T) || hasNext;
            bf16x8 af[4][2], b0[2][2], b1[2][2];

            // ---------- ph0 ----------
#pragma unroll
            for (int m = 0; m < 4; ++m)
#pragma unroll
                for (int kk = 0; kk < 2; ++kk)
                    af[m][kk] = *(const bf16x8*)&Ab[(arow + m * 16) * 64 + ((((kk << 2) | q) ^ xsw) << 3)];
#pragma unroll
            for (int n = 0; n < 2; ++n)
#pragma unroll
                for (int kk = 0; kk < 2; ++kk)
                    b0[n][kk] = *(const bf16x8*)&Bb[(brow + n * 16) * 64 + ((((kk << 2) | q) ^ xsw) << 3)];
            if (more) stageA(u + 1, 0);
            __builtin_amdgcn_s_setprio(1);
#pragma unroll
            for (int kk = 0; kk < 2; ++kk)
#pragma unroll
                for (int m = 0; m < 4; ++m)
#pragma unroll
                    for (int n = 0; n < 2; ++n)
                        acc[m][n] = __builtin_amdgcn_mfma_f32_16x16x32_bf16(af[m][kk], b0[n][kk], acc[m][n], 0, 0, 0);
            __builtin_amdgcn_s_setprio(0);

            // ---------- ph1 ----------
            if (more) asm volatile("s_waitcnt vmcnt(4)" ::: "memory");
            else      asm volatile("s_waitcnt vmcnt(2)" ::: "memory");
            __builtin_amdgcn_s_barrier();
            asm volatile("" ::: "memory");
#pragma unroll
            for (int n = 0; n < 2; ++n)
#pragma unroll
                for (int kk = 0; kk < 2; ++kk)
                    b1[n][kk] = *(const bf16x8*)&Bb[(brow + 32 + n * 16) * 64 + ((((kk << 2) | q) ^ xsw) << 3)];
            if (more) stageB(u + 1, 0);
            __builtin_amdgcn_s_setprio(1);
#pragma unroll
            for (int kk = 0; kk < 2; ++kk)
#pragma unroll
                for (int m = 0; m < 4; ++m)
#pragma unroll
                    for (int n = 0; n < 2; ++n)
                        acc[m][2 + n] = __builtin_amdgcn_mfma_f32_16x16x32_bf16(af[m][kk], b1[n][kk], acc[m][2 + n], 0, 0, 0);
            __builtin_amdgcn_s_setprio(0);

            // ---------- ph2 ----------
            if (more) asm volatile("s_waitcnt vmcnt(4)" ::: "memory");
            else      asm volatile("s_waitcnt vmcnt(0)" ::: "memory");
            __builtin_amdgcn_s_barrier();
            asm volatile("" ::: "memory");
#pragma unroll
            for (int m = 0; m < 4; ++m)
#pragma unroll
                for (int kk = 0; kk < 2; ++kk)
                    af[m][kk] = *(const bf16x8*)&Ab[(arow + 64 + m * 16) * 64 + ((((kk << 2) | q) ^ xsw) << 3)];
            if (more) stageB(u + 1, 1);
            __builtin_amdgcn_s_setprio(1);
#pragma unroll
            for (int kk = 0; kk < 2; ++kk)
#pragma unroll
                for (int m = 0; m < 4; ++m)
#pragma unroll
                    for (int n = 0; n < 2; ++n)
                        acc[4 + m][2 + n] = __builtin_amdgcn_mfma_f32_16x16x32_bf16(af[m][kk], b1[n][kk], acc[4 + m][2 + n], 0, 0, 0);
            __builtin_amdgcn_s_setprio(0);

            // ---------- ph3 ----------
            if (more) {
                stageA(u + 1, 1);
                asm volatile("s_waitcnt vmcnt(4)" ::: "memory");
                __builtin_amdgcn_s_barrier();
                asm volatile("" ::: "memory");
            }
            __builtin_amdgcn_s_setprio(1);
#pragma unroll
            for (int kk = 0; kk < 2; ++kk)
#pragma unroll
                for (int m = 0; m < 4; ++m)
#pragma unroll
                    for (int n = 0; n < 2; ++n)
                        acc[4 + m][n] = __builtin_amdgcn_mfma_f32_16x16x32_bf16(af[m][kk], b0[n][kk], acc[4 + m][n], 0, 0, 0);
            __builtin_amdgcn_s_setprio(0);
        }

        // ---------------- coalesced epilogue ----------------
        __syncthreads();

        float bshift[2][2];
        if (BIAS) {
#pragma unroll
            for (int nh = 0; nh < 2; ++nh)
#pragma unroll
                for (int n = 0; n < 2; ++n)
                    bshift[nh][n] = bias[tileN + wn + nh * 32 + n * 16 + l16];
        }

        if constexpr (!OUTF) {
            unsigned short* slab = AsP + 16384 + (size_t)w * 1152;
            unsigned short* co = (unsigned short*)Cout;
#pragma unroll
            for (int mh = 0; mh < 2; ++mh)
#pragma unroll
                for (int m = 0; m < 4; ++m) {
#pragma unroll
                    for (int nh = 0; nh < 2; ++nh)
#pragma unroll
                        for (int n = 0; n < 2; ++n)
#pragma unroll
                            for (int r2 = 0; r2 < 4; ++r2) {
                                float v = acc[mh * 4 + m][nh * 2 + n][r2];
                                if (BIAS) v += bshift[nh][n];
                                if (GELU) v = gelu_f(v);
                                slab[(q * 4 + r2) * 72 + nh * 32 + n * 16 + l16] = f2b(v);
                            }
#pragma unroll
                    for (int h = 0; h < 2; ++h) {
                        const int lr = h * 8 + (lane >> 3);
                        const int grow = tileM + wm + mh * 64 + m * 16 + lr;
                        const int gcol = tileN + wn + (lane & 7) * 8;
                        uint4 pk = *(const uint4*)&slab[lr * 72 + (lane & 7) * 8];
                        if (RES != 0) {
                            unsigned short* ps = (unsigned short*)&pk;
#pragma unroll
                            for (int j = 0; j < 8; ++j) {
                                float v = b2f(ps[j]);
                                if (RES == 1) v += ((const float*)resid)[(size_t)grow * N + gcol + j];
                                if (RES == 2) v += b2f(((const unsigned short*)resid)[(size_t)grow * N + gcol + j]);
                                ps[j] = f2b(v);
                            }
                        }
                        *(uint4*)&co[(size_t)grow * N + gcol] = pk;
                    }
                }
        } else {
            float* slabf = (w == 7) ? (float*)(BsP + 16384)
                                    : (float*)(AsP + 16384) + (size_t)w * 1088;
            float* co = (float*)Cout;
#pragma unroll
            for (int mh = 0; mh < 2; ++mh)
#pragma unroll
                for (int m = 0; m < 4; ++m) {
#pragma unroll
                    for (int nh = 0; nh < 2; ++nh)
#pragma unroll
                        for (int n = 0; n < 2; ++n)
#pragma unroll
                            for (int r2 = 0; r2 < 4; ++r2) {
                                float v = acc[mh * 4 + m][nh * 2 + n][r2];
                                if (BIAS) v += bshift[nh][n];
                                if (GELU) v = gelu_f(v);
                                slabf[(q * 4 + r2) * 68 + nh * 32 + n * 16 + l16] = v;
                            }
#pragma unroll
                    for (int i4 = 0; i4 < 4; ++i4) {
                        const int lr = i4 * 4 + (lane >> 4);
                        const int grow = tileM + wm + mh * 64 + m * 16 + lr;
                        const int gcol = tileN + wn + (lane & 15) * 4;
                        f32x4 vv = *(const f32x4*)&slabf[lr * 68 + (lane & 15) * 4];
                        if (RES == 1) {
                            const float4 r4 = *(const float4*)&((const float*)resid)[(size_t)grow * N + gcol];
                            vv[0] += r4.x; vv[1] += r4.y; vv[2] += r4.z; vv[3] += r4.w;
                        }
                        if (RES == 2) {
                            const ushort4 r4 = *(const ushort4*)&((const unsigned short*)resid)[(size_t)grow * N + gcol];
                            vv[0] += b2f(r4.x); vv[1] += b2f(r4.y); vv[2] += b2f(r4.z); vv[3] += b2f(r4.w);
                        }
                        *(f32x4*)&co[(size_t)grow * N + gcol] = vv;
                    }
                }
        }

        if (hasNext) {
            asm volatile("s_waitcnt vmcnt(4)" ::: "memory");
            __syncthreads();
        }
    }
}

// ---------------- standalone gemm8p kernel (fallback path) ----------------
template<int KC, bool BIAS, int RES, bool GELU, bool OUTF>
__global__ __launch_bounds__(512, 2)
void gemm8p(const unsigned short* __restrict__ A,
            const unsigned short* __restrict__ Bw,
            const float* __restrict__ bias,
            const void* __restrict__ resid,
            void* __restrict__ Cout,
            int M, int N)
{
    __shared__ __align__(16) unsigned short AsS[2 * 16384];
    __shared__ __align__(16) unsigned short BsS[2 * 16384];
    gemm8p_body<KC, BIAS, RES, GELU, OUTF>(A, Bw, bias, resid, Cout, M, N, AsS, BsS);
}

// ---------------- cooperative kernels ----------------
struct CoopAArgs {
    const float* x; const float* g1; const float* b1; unsigned short* hbuf;
    const float* s0; unsigned short* d0; int n0;
    const float* s1; unsigned short* d1; int n1;
    const float* s2; unsigned short* d2; int n2;
    const float* s3; unsigned short* d3; int n3;
    const unsigned short* wqk; unsigned short* qkbuf;
};

__global__ __launch_bounds__(512, 2) void coopA(CoopAArgs a)
{
    __shared__ __align__(16) unsigned short AsS[2 * 16384];
    __shared__ __align__(16) unsigned short BsS[2 * 16384];
    __shared__ __align__(16) float red[16];
    ln_phase<true>(a.x, a.g1, a.b1, a.hbuf, red);
    conv_phase(a.s0, a.d0, a.n0, a.s1, a.d1, a.n1, a.s2, a.d2, a.n2, a.s3, a.d3, a.n3);
    __threadfence();
    cg::this_grid().sync();
    gemm8p_body<CH, false, 0, false, false>(a.hbuf, a.wqk, nullptr, nullptr, a.qkbuf,
                                            MROWS, 2 * CH, AsS, BsS);
}

struct CoopBArgs {
    const unsigned short* x1b; const float* g2; const float* b2; unsigned short* hbuf;
    const unsigned short* wf1; const float* f1b; unsigned short* gg;
    const unsigned short* wf2; const float* f2b; float* out;
};

__global__ __launch_bounds__(512, 2) void coopB(CoopBArgs b)
{
    __shared__ __align__(16) unsigned short AsS[2 * 16384];
    __shared__ __align__(16) unsigned short BsS[2 * 16384];
    __shared__ __align__(16) float red[16];
    ln_phase<false>(b.x1b, b.g2, b.b2, b.hbuf, red);
    __threadfence();
    cg::this_grid().sync();
    gemm8p_body<CH, true, 0, true, false>(b.hbuf, b.wf1, b.f1b, nullptr, b.gg,
                                          MROWS, HID, AsS, BsS);
    __threadfence();
    cg::this_grid().sync();
    gemm8p_body<HID, true, 2, false, true>(b.gg, b.wf2, b.f2b, b.x1b, b.out,
                                           MROWS, CH, AsS, BsS);
}

// ---------------- prep (fallback): LN1 + weights, one dispatch ----------------
__global__ __launch_bounds__(256) void prep_k(const float* __restrict__ x,
                                              const float* __restrict__ gw,
                                              const float* __restrict__ bw,
                                              unsigned short* __restrict__ hbuf,
                                              const float* __restrict__ s0, unsigned short* __restrict__ d0, int n0,
                                              const float* __restrict__ s1, unsigned short* __restrict__ d1, int n1,
                                              const float* __restrict__ s2, unsigned short* __restrict__ d2, int n2,
                                              const float* __restrict__ s3, unsigned short* __restrict__ d3, int n3)
{
    const int bid = blockIdx.x;
    const int tid = threadIdx.x;
    __shared__ __align__(16) float red[8];
    if (bid < MROWS) {
        const float* xr = x + (size_t)bid * CH;
        float v0 = xr[tid], v1 = xr[tid + 256], v2 = xr[tid + 512];
        float s  = v0 + v1 + v2;
        float sq = v0*v0 + v1*v1 + v2*v2;
#pragma unroll
        for (int off = 32; off > 0; off >>= 1) {
            s  += __shfl_down(s, off, 64);
            sq += __shfl_down(sq, off, 64);
        }
        if ((tid & 63) == 0) { red[(tid >> 6) * 2] = s; red[(tid >> 6) * 2 + 1] = sq; }
        __syncthreads();
        s  = red[0] + red[2] + red[4] + red[6];
        sq = red[1] + red[3] + red[5] + red[7];
        float mu  = s * (1.0f / CH);
        float var = sq * (1.0f / CH) - mu * mu;
        float rs  = rsqrtf(var + 1e-5f);
        unsigned short* orow = hbuf + (size_t)bid * CH;
        orow[tid]       = f2b((v0 - mu) * rs * gw[tid]       + bw[tid]);
        orow[tid + 256] = f2b((v1 - mu) * rs * gw[tid + 256] + bw[tid + 256]);
        orow[tid + 512] = f2b((v2 - mu) * rs * gw[tid + 512] + bw[tid + 512]);
    } else {
        int idx = ((bid - MROWS) * 256 + tid) * 4;
        const float* s; unsigned short* d; int n;
        if (idx < n0) { s = s0; d = d0; n = n0; }
        else {
            idx -= n0;
            if (idx < n1) { s = s1; d = d1; n = n1; }
            else {
                idx -= n1;
                if (idx < n2) { s = s2; d = d2; n = n2; }
                else { idx -= n2; s = s3; d = d3; n = n3; }
            }
        }
        if (idx < n) {
            float4 v = *(const float4*)(s + idx);
            ushort4 o;
            o.x = f2b(v.x); o.y = f2b(v.y); o.z = f2b(v.z); o.w = f2b(v.w);
            *(ushort4*)(d + idx) = o;
        }
    }
}

// ---------------- LayerNorm kernel (fallback): one block per row ----------------
template<bool INF32>
__global__ __launch_bounds__(256) void ln_k(const void* __restrict__ xin,
                                            const float* __restrict__ gw,
                                            const float* __restrict__ bw,
                                            unsigned short* __restrict__ out)
{
    const int row = blockIdx.x;
    const int tid = threadIdx.x;
    float v0, v1, v2;
    if constexpr (INF32) {
        const float* xr = (const float*)xin + (size_t)row * CH;
        v0 = xr[tid]; v1 = xr[tid + 256]; v2 = xr[tid + 512];
    } else {
        const unsigned short* xr = (const unsigned short*)xin + (size_t)row * CH;
        v0 = b2f(xr[tid]); v1 = b2f(xr[tid + 256]); v2 = b2f(xr[tid + 512]);
    }
    float s  = v0 + v1 + v2;
    float sq = v0*v0 + v1*v1 + v2*v2;
#pragma unroll
    for (int off = 32; off > 0; off >>= 1) {
        s  += __shfl_down(s, off, 64);
        sq += __shfl_down(sq, off, 64);
    }
    __shared__ __align__(16) float red[8];
    if ((tid & 63) == 0) { red[(tid >> 6) * 2] = s; red[(tid >> 6) * 2 + 1] = sq; }
    __syncthreads();
    s  = red[0] + red[2] + red[4] + red[6];
    sq = red[1] + red[3] + red[5] + red[7];
    float mu  = s * (1.0f / CH);
    float var = sq * (1.0f / CH) - mu * mu;
    float rs  = rsqrtf(var + 1e-5f);
    unsigned short* orow = out + (size_t)row * CH;
    orow[tid]       = f2b((v0 - mu) * rs * gw[tid]       + bw[tid]);
    orow[tid + 256] = f2b((v1 - mu) * rs * gw[tid + 256] + bw[tid + 256]);
    orow[tid + 512] = f2b((v2 - mu) * rs * gw[tid + 512] + bw[tid + 512]);
}

// ---------------- NT GEMM (legacy 2-barrier): C = A @ W^T (+bias)(+gelu)(+resid) ----
// Kept for attn-proj (K=192) and halved fallback paths.
template<int TM, int TN, bool BIAS, int RES, bool GELU, bool OUTF>
__global__ __launch_bounds__(256, 4)
void gemm_bt(const unsigned short* __restrict__ A,
             const unsigned short* __restrict__ Bw,
             const float* __restrict__ bias,
             const void* __restrict__ resid,
             void* __restrict__ Cout,
             int M, int N, int K)
{
    constexpr int WROWS = (TM == 128) ? 2 : 1;
    constexpr int WCOLS = 4 / WROWS;
    constexpr int JF = TN / (16 * WCOLS);
    __shared__ __align__(16) unsigned short As[2][TM * 32];
    __shared__ __align__(16) unsigned short Bs[2][TN * 32];
    const int tid  = threadIdx.x;
    const int w    = tid >> 6;
    const int lane = tid & 63;

    const int gridN = gridDim.x, gridM = gridDim.y;
    const int lid = blockIdx.y * gridN + blockIdx.x;
    const int SG = 8 * gridN;
    const int sg = lid / SG, r = lid % SG;
    const int remM = gridM - sg * 8;
    int mloc, nloc;
    if (remM >= 8) { mloc = sg * 8 + (r & 7); nloc = r >> 3; }
    else           { mloc = sg * 8 + r % remM; nloc = r / remM; }
    const int tileM = mloc * TM;
    const int tileN = nloc * TN;

    const int wm = (w / WCOLS) * 64;
    const int wn = (w % WCOLS) * (JF * 16);
    const int q   = lane >> 4;
    const int l16 = lane & 15;
    const int csw = (q ^ (l16 & 3)) * 8;

    f32x4 acc[4][JF];
#pragma unroll
    for (int i = 0; i < 4; ++i)
#pragma unroll
        for (int j = 0; j < JF; ++j) acc[i][j] = (f32x4){0.f, 0.f, 0.f, 0.f};

    const int r0 = tid >> 2;
    const int g0 = ((tid & 3) ^ (r0 & 3)) * 8;

    const unsigned short* pB[TN / 64];
    const unsigned short* pA[TM / 64];
#pragma unroll
    for (int c = 0; c < TN / 64; ++c) pB[c] = Bw + (size_t)(tileN + r0 + c * 64) * K + g0;
#pragma unroll
    for (int c = 0; c < TM / 64; ++c) pA[c] = A + (size_t)(tileM + r0 + c * 64) * K + g0;

    auto stage = [&](int buf) {
#pragma unroll
        for (int c = 0; c < TN / 64; ++c) {
            async16(pB[c], &Bs[buf][(size_t)(c * 256 + w * 64) * 8]);
            pB[c] += 32;
        }
#pragma unroll
        for (int c = 0; c < TM / 64; ++c) {
            async16(pA[c], &As[buf][(size_t)(c * 256 + w * 64) * 8]);
            pA[c] += 32;
        }
    };

    const int kIters = K >> 5;
    stage(0);
    int cur = 0;
    for (int kt = 0; kt < kIters; ++kt) {
        __syncthreads();
        if (kt + 1 < kIters) stage(cur ^ 1);
        bf16x8 af[4], bfr[JF];
#pragma unroll
        for (int i = 0; i < 4; ++i)
            af[i] = *(const bf16x8*)&As[cur][(wm + i * 16 + l16) * 32 + csw];
#pragma unroll
        for (int j = 0; j < JF; ++j)
            bfr[j] = *(const bf16x8*)&Bs[cur][(wn + j * 16 + l16) * 32 + csw];
#pragma unroll
        for (int i = 0; i < 4; ++i)
#pragma unroll
            for (int j = 0; j < JF; ++j)
                acc[i][j] = __builtin_amdgcn_mfma_f32_16x16x32_bf16(af[i], bfr[j], acc[i][j], 0, 0, 0);
        cur ^= 1;
    }

#pragma unroll
    for (int i = 0; i < 4; ++i) {
#pragma unroll
        for (int r2 = 0; r2 < 4; ++r2) {
            int row = tileM + wm + i * 16 + q * 4 + r2;
#pragma unroll
            for (int j = 0; j < JF; ++j) {
                int col = tileN + wn + j * 16 + l16;
                float v = acc[i][j][r2];
                if (BIAS) v += bias[col];
                if (GELU) v = gelu_f(v);
                if (RES == 1) v += ((const float*)resid)[(size_t)row * N + col];
                if (RES == 2) v += b2f(((const unsigned short*)resid)[(size_t)row * N + col]);
                if (OUTF) ((float*)Cout)[(size_t)row * N + col] = v;
                else      ((unsigned short*)Cout)[(size_t)row * N + col] = f2b(v);
            }
        }
    }
}

// ---------------- Attention: MFMA scores + med3 top-16 + softmax ----------------
__global__ __launch_bounds__(256) void attn_topk(const unsigned short* __restrict__ qk,
                                                 unsigned short* __restrict__ aout)
{
    const int bh = blockIdx.x;
    const int b = bh / NHEAD, h = bh % NHEAD;
    __shared__ __align__(16) unsigned short Qs[208 * 64];
    __shared__ __align__(16) unsigned short Ks[208 * 64];
    const int tid = threadIdx.x;

    for (int i = tid; i < 208 * 8; i += 256) {
        int row = i >> 3, c = i & 7;
        uint4 vq = make_uint4(0, 0, 0, 0), vk = vq;
        if (row < SEQ) {
            const uint4* gp = (const uint4*)(qk + ((size_t)(b * SEQ + row) * 1536 + h * 64));
            vq = gp[c];
            vk = gp[c + 96];
        }
        int slot = c ^ (row & 7);
        *(uint4*)&Qs[row * 64 + slot * 8] = vq;
        *(uint4*)&Ks[row * 64 + slot * 8] = vk;
    }
    __syncthreads();

    const int w = tid >> 6, lane = tid & 63;
    const int q = lane >> 4, l16 = lane & 15;

    for (int tn = w; tn < 13; tn += 4) {
        const int nrow = tn * 16 + l16;
        const int nsw = nrow & 7;
        bf16x8 bq0 = *(const bf16x8*)&Qs[nrow * 64 + ((0 * 4 + q) ^ nsw) * 8];
        bf16x8 bq1 = *(const bf16x8*)&Qs[nrow * 64 + ((1 * 4 + q) ^ nsw) * 8];

        float t[TOPK];
#pragma unroll
        for (int j = 0; j < TOPK; ++j) t[j] = NEGBIG;

        for (int tm = 0; tm < 12; ++tm) {
            const int mrow = tm * 16 + l16;
            const int msw = mrow & 7;
            bf16x8 ak0 = *(const bf16x8*)&Ks[mrow * 64 + ((0 * 4 + q) ^ msw) * 8];
            bf16x8 ak1 = *(const bf16x8*)&Ks[mrow * 64 + ((1 * 4 + q) ^ msw) * 8];
            f32x4 acc = (f32x4){0.f, 0.f, 0.f, 0.f};
            acc = __builtin_amdgcn_mfma_f32_16x16x32_bf16(ak0, bq0, acc, 0, 0, 0);
            acc = __builtin_amdgcn_mfma_f32_16x16x32_bf16(ak1, bq1, acc, 0, 0, 0);
#pragma unroll
            for (int r = 0; r < 4; ++r) {
                float v = acc[r];
#pragma unroll
                for (int j = TOPK - 1; j >= 1; --j)
                    t[j] = med3(v, t[j], t[j - 1]);
                t[0] = fmaxf(t[0], v);
            }
        }
        {   // m-tile 12: m = 192 + q*4 + r valid only for q==0
            const int mrow = 12 * 16 + l16;
            const int msw = mrow & 7;
            bf16x8 ak0 = *(const bf16x8*)&Ks[mrow * 64 + ((0 * 4 + q) ^ msw) * 8];
            bf16x8 ak1 = *(const bf16x8*)&Ks[mrow * 64 + ((1 * 4 + q) ^ msw) * 8];
            f32x4 acc = (f32x4){0.f, 0.f, 0.f, 0.f};
            acc = __builtin_amdgcn_mfma_f32_16x16x32_bf16(ak0, bq0, acc, 0, 0, 0);
            acc = __builtin_amdgcn_mfma_f32_16x16x32_bf16(ak1, bq1, acc, 0, 0, 0);
#pragma unroll
            for (int r = 0; r < 4; ++r) {
                float v = (q == 0) ? acc[r] : NEGBIG;
#pragma unroll
                for (int j = TOPK - 1; j >= 1; --j)
                    t[j] = med3(v, t[j], t[j - 1]);
                t[0] = fmaxf(t[0], v);
            }
        }

#pragma unroll
        for (int stage = 0; stage < 2; ++stage) {
            const int xm = 16 << stage;
            float bl[TOPK], c[TOPK];
#pragma unroll
            for (int j = 0; j < TOPK; ++j) bl[j] = __shfl_xor(t[j], xm, 64);
#pragma unroll
            for (int j = 0; j < TOPK; ++j) c[j] = fmaxf(t[j], bl[TOPK - 1 - j]);
#pragma unroll
            for (int s = 8; s >= 1; s >>= 1) {
#pragma unroll
                for (int i = 0; i < TOPK; ++i) {
                    if ((i & s) == 0) {
                        float mx = fmaxf(c[i], c[i + s]);
                        c[i + s] = fminf(c[i], c[i + s]);
                        c[i] = mx;
                    }
                }
            }
#pragma unroll
            for (int j = 0; j < TOPK; ++j) t[j] = c[j];
        }

        if (q == 0 && nrow < SEQ) {
            float e[TOPK], sum = 0.f;
#pragma unroll
            for (int j = 0; j < TOPK; ++j) { e[j] = __expf((t[j] - t[0]) * SCALE_F); sum += e[j]; }
            float inv = 1.0f / sum;
            unsigned int pk[8];
#pragma unroll
            for (int jj = 0; jj < 8; ++jj)
                pk[jj] = (unsigned int)f2b(e[2 * jj] * inv) |
                         ((unsigned int)f2b(e[2 * jj + 1] * inv) << 16);
            unsigned short* dst = aout + ((size_t)(b * SEQ + nrow)) * (NHEAD * TOPK) + h * TOPK;
            ((uint4*)dst)[0] = make_uint4(pk[0], pk[1], pk[2], pk[3]);
            ((uint4*)dst)[1] = make_uint4(pk[4], pk[5], pk[6], pk[7]);
        }
    }
}

// ---------------- Launch ----------------
extern "C" void kernel_launch(void* const* d_in, const int* in_sizes, int n_in,
                              void* d_out, int out_size, void* d_ws, size_t ws_size,
                              hipStream_t stream)
{
    const float* x    = (const float*)d_in[0];
    const float* g1   = (const float*)d_in[1];
    const float* bb1  = (const float*)d_in[2];
    const float* qkw  = (const float*)d_in[3];
    const float* pw   = (const float*)d_in[4];
    const float* pb   = (const float*)d_in[5];
    const float* g2   = (const float*)d_in[6];
    const float* bb2  = (const float*)d_in[7];
    const float* f1w  = (const float*)d_in[8];
    const float* f1b  = (const float*)d_in[9];
    const float* f2w  = (const float*)d_in[10];
    const float* f2bp = (const float*)d_in[11];
    float* out = (float*)d_out;

    // layout: hbuf | weights(wqk,wp,wf1,wf2) | av | qk/gg | x1b
    char* ws = (char*)d_ws;
    const size_t SZ_H   = (size_t)MROWS * CH * 2;              // 19,267,584
    const size_t N_WQK  = (size_t)2 * CH * CH;
    const size_t N_WP   = (size_t)CH * (NHEAD * TOPK);
    const size_t N_WF   = (size_t)HID * CH;
    const size_t SZ_W   = (N_WQK + N_WP + 2 * N_WF) * 2;       // 12,091,392
    const size_t SZ_A   = (size_t)MROWS * (NHEAD * TOPK) * 2;  //  4,816,896
    const size_t SZ_QK  = (size_t)MROWS * 2 * CH * 2;          // 38,535,168
    const size_t SZ_GGF = (size_t)MROWS * HID * 2;             // 77,070,336

    unsigned short* hbuf = (unsigned short*)(ws);
    unsigned short* wqk  = (unsigned short*)(ws + SZ_H);
    unsigned short* wp   = wqk + N_WQK;
    unsigned short* wf1  = wp  + N_WP;
    unsigned short* wf2  = wf1 + N_WF;
    unsigned short* av   = (unsigned short*)(ws + SZ_H + SZ_W);
    unsigned short* qk   = (unsigned short*)(ws + SZ_H + SZ_W + SZ_A);
    unsigned short* gg   = qk;   // overlays qk (dead by MLP time)

    const size_t base = SZ_H + SZ_W + SZ_A;
    const bool fullMLP = ws_size >= base + SZ_GGF + SZ_H;      // 132.5 MB
    const bool bx1     = fullMLP || ws_size >= base + SZ_QK + SZ_H;
    unsigned short* x1b = (unsigned short*)(ws + base + (fullMLP ? SZ_GGF : SZ_QK));
    float* x1 = out;

    const int total4 = (int)((N_WQK + N_WP + 2 * N_WF) / 4);
    const int wblk   = (total4 + 255) / 256;

    if (fullMLP) {
        // ---- coopA: [LN1 + weight-convert] -> grid.sync -> [qk] ----
        CoopAArgs pa { x, g1, bb1, hbuf,
                       qkw, wqk, (int)N_WQK, pw, wp, (int)N_WP,
                       f1w, wf1, (int)N_WF, f2w, wf2, (int)N_WF,
                       wqk, qk };
        void* argsA[] = { &pa };
        hipError_t eA = hipLaunchCooperativeKernel((const void*)coopA, dim3(256), dim3(512),
                                                   argsA, 0, stream);
        if (eA != hipSuccess) {
            prep_k<<<MROWS + wblk, 256, 0, stream>>>(
                x, g1, bb1, hbuf,
                qkw, wqk, (int)N_WQK, pw, wp, (int)N_WP,
                f1w, wf1, (int)N_WF, f2w, wf2, (int)N_WF);
            gemm8p<CH, false, 0, false, false><<<256, 512, 0, stream>>>(
                hbuf, wqk, nullptr, nullptr, qk, MROWS, 2 * CH);
        }

        // ---- attention + proj (unchanged, verified) ----
        attn_topk<<<BATCH * NHEAD, 256, 0, stream>>>(qk, av);
        gemm_bt<64, 128, true, 1, false, false><<<dim3(6, 196), 256, 0, stream>>>(
            av, wp, pb, x, x1b, MROWS, CH, NHEAD * TOPK);

        // ---- coopB: [LN2] -> sync -> [fc1] -> sync -> [fc2] ----
        CoopBArgs pbb { x1b, g2, bb2, hbuf, wf1, f1b, gg, wf2, f2bp, out };
        void* argsB[] = { &pbb };
        hipError_t eB = hipLaunchCooperativeKernel((const void*)coopB, dim3(256), dim3(512),
                                                   argsB, 0, stream);
        if (eB != hipSuccess) {
            ln_k<false><<<MROWS, 256, 0, stream>>>(x1b, g2, bb2, hbuf);
            gemm8p<CH, true, 0, true, false><<<256, 512, 0, stream>>>(
                hbuf, wf1, f1b, nullptr, gg, MROWS, HID);
            gemm8p<HID, true, 2, false, true><<<147, 512, 0, stream>>>(
                gg, wf2, f2bp, x1b, out, MROWS, CH);
        }
    } else {
        // classic sequence (R11) for reduced-workspace configurations
        prep_k<<<MROWS + wblk, 256, 0, stream>>>(
            x, g1, bb1, hbuf,
            qkw, wqk, (int)N_WQK, pw, wp, (int)N_WP,
            f1w, wf1, (int)N_WF, f2w, wf2, (int)N_WF);
        gemm8p<CH, false, 0, false, false><<<256, 512, 0, stream>>>(
            hbuf, wqk, nullptr, nullptr, qk, MROWS, 2 * CH);
        attn_topk<<<BATCH * NHEAD, 256, 0, stream>>>(qk, av);
        if (bx1) {
            gemm_bt<64, 128, true, 1, false, false><<<dim3(6, 196), 256, 0, stream>>>(
                av, wp, pb, x, x1b, MROWS, CH, NHEAD * TOPK);
            ln_k<false><<<MROWS, 256, 0, stream>>>(x1b, g2, bb2, hbuf);
            for (int half = 0; half < 2; ++half) {
                const size_t ro = (size_t)half * MHALF;
                gemm_bt<128, 128, true, 0, true, false><<<dim3(24, 49), 256, 0, stream>>>(
                    hbuf + ro * CH, wf1, f1b, nullptr, gg, MHALF, HID, CH);
                gemm_bt<64, 256, true, 2, false, true><<<dim3(3, 98), 256, 0, stream>>>(
                    gg, wf2, f2bp, x1b + ro * CH, out + ro * CH, MHALF, CH, HID);
            }
        } else {
            gemm_bt<64, 128, true, 1, false, true><<<dim3(6, 196), 256, 0, stream>>>(
                av, wp, pb, x, x1, MROWS, CH, NHEAD * TOPK);
            ln_k<true><<<MROWS, 256, 0, stream>>>(x1, g2, bb2, hbuf);
            for (int half = 0; half < 2; ++half) {
                const size_t ro = (size_t)half * MHALF;
                gemm_bt<128, 128, true, 0, true, false><<<dim3(24, 49), 256, 0, stream>>>(
                    hbuf + ro * CH, wf1, f1b, nullptr, gg, MHALF, HID, CH);
                gemm_bt<64, 256, true, 1, false, true><<<dim3(3, 98), 256, 0, stream>>>(
                    gg, wf2, f2bp, x1 + ro * CH, out + ro * CH, MHALF, CH, HID);
            }
        }
    }
}